// Round 5
// baseline (95.921 us; speedup 1.0000x reference)
//
#include <hip/hip_runtime.h>
#include <math.h>

// BispectrumCalculator:
//   y = fft(target)  [B,T,N] complex
//   Bx[k,l] = y[k] * conj(y[l]) * y[(l-k) mod N]
//   source = stack([Bx.re, Bx.im], ch).mean(T)  -> [B, 2, N, N]
//   outputs: (source, target)  -> d_out = source flat (16,777,216) ++ target flat (65,536)
//
// Window model (r2-r4 post-mortems): harness re-poison of d_ws (269 MB,
// ~46us) + d_out (67 MB, ~11us) is inside the measured window; controllable
// slice ~30us = bispec (~12, store floor 10.7) + dft (~2) + dispatch gaps.

#define NN 512
#define TT 4
#define BB 32
#define PAD 16            // ring stride = NN+PAD; windows over-run end by <=7

// ---------------------------------------------------------------------------
// Kernel A: DFT-512 per (b,t), n-split for occupancy (unchanged from r4).
// Grid = 512 blocks x 256 threads; tid = nh*128+kl, k = kq*128+kl.
// Rotor seeds via exact mod-512 phase reduction; nh=1 partials via LDS.
// kq==0 also copies the target row to the output tail (fused passthrough).
// ---------------------------------------------------------------------------
__global__ __launch_bounds__(256) void dft_kernel(const float* __restrict__ x,
                                                  float2* __restrict__ y,
                                                  float* __restrict__ tail) {
    __shared__ float2 part[128];

    int bt = blockIdx.x >> 2;
    int kq = blockIdx.x & 3;
    int kl = threadIdx.x & 127;
    int nh = threadIdx.x >> 7;
    int k  = (kq << 7) | kl;
    const float* xp = x + (size_t)bt * NN;

    if (kq == 0 && nh == 0) {
        ((float4*)(tail + (size_t)bt * NN))[kl] = ((const float4*)xp)[kl];
    }

    int n0 = nh << 8;  // 0 or 256
    const float twopi_n = -2.0f * (float)M_PI / (float)NN;

    float2 w0, w1, w2, w3;
    float s4, c4;
    {
        int m0 = (k * (n0 + 0)) & (NN - 1);
        int m1 = (k * (n0 + 1)) & (NN - 1);
        int m2 = (k * (n0 + 2)) & (NN - 1);
        int m3 = (k * (n0 + 3)) & (NN - 1);
        int m4 = (k * 4) & (NN - 1);
        sincosf(twopi_n * (float)m0, &w0.y, &w0.x);
        sincosf(twopi_n * (float)m1, &w1.y, &w1.x);
        sincosf(twopi_n * (float)m2, &w2.y, &w2.x);
        sincosf(twopi_n * (float)m3, &w3.y, &w3.x);
        sincosf(twopi_n * (float)m4, &s4, &c4);
    }

    float2 a0 = make_float2(0.f, 0.f), a1 = a0, a2 = a0, a3 = a0;

    #pragma unroll 4
    for (int n = n0; n < n0 + 256; n += 4) {
        float x0 = xp[n];
        float x1 = xp[n + 1];
        float x2 = xp[n + 2];
        float x3 = xp[n + 3];
        a0.x += x0 * w0.x; a0.y += x0 * w0.y;
        a1.x += x1 * w1.x; a1.y += x1 * w1.y;
        a2.x += x2 * w2.x; a2.y += x2 * w2.y;
        a3.x += x3 * w3.x; a3.y += x3 * w3.y;
        float t;
        t = w0.x * c4 - w0.y * s4; w0.y = w0.x * s4 + w0.y * c4; w0.x = t;
        t = w1.x * c4 - w1.y * s4; w1.y = w1.x * s4 + w1.y * c4; w1.x = t;
        t = w2.x * c4 - w2.y * s4; w2.y = w2.x * s4 + w2.y * c4; w2.x = t;
        t = w3.x * c4 - w3.y * s4; w3.y = w3.x * s4 + w3.y * c4; w3.x = t;
    }

    float re = (a0.x + a1.x) + (a2.x + a3.x);
    float im = (a0.y + a1.y) + (a2.y + a3.y);

    if (nh == 1) {
        part[kl] = make_float2(re, im);
    }
    __syncthreads();
    if (nh == 0) {
        float2 p = part[kl];
        y[(size_t)bt * NN + k] = make_float2(re + p.x, im + p.y);
    }
}

// ---------------------------------------------------------------------------
// Kernel B: bispectrum, sliding-window with PADDED ring (r5).
// Grid = B * 64 blocks of 256 threads; block = one b, 8 consecutive k-rows.
// Ring stride NN+PAD: windows (max index 518) stay contiguous without the
// 2x doubled ring of r3/r4 -> LDS 32 -> 16.5 KiB, staging writes halved.
// t=0 peeled into accumulator init; nontemporal output stores (write-once).
// ---------------------------------------------------------------------------
__global__ __launch_bounds__(256) void bispec_kernel(const float2* __restrict__ y,
                                                     float* __restrict__ out) {
    __shared__ float2 ring[TT][NN + PAD];  // 16.5 KiB

    int b     = blockIdx.x >> 6;
    int kbase = (blockIdx.x & 63) << 3;
    int tid   = threadIdx.x;

    const float2* yb = y + (size_t)b * TT * NN;

    // stage y[b] -> ring (1024 float4 across 256 threads)
    const float4* src = (const float4*)yb;
    #pragma unroll
    for (int i = 0; i < 4; ++i) {
        int g = tid + 256 * i;          // [0,1024)
        int t = g >> 8;
        int j = g & 255;
        ((float4*)ring[t])[j] = src[g];
    }
    // pad: first 8 entries duplicated past the end (read from global: no
    // LDS->LDS dependency, single barrier)
    if (tid < TT * 8) {
        int t = tid >> 3;
        int j = tid & 7;
        ring[t][NN + j] = yb[t * NN + j];
    }
    __syncthreads();

    int l0 = tid;  // second l is l0 + 256

    // conj-source values, k-invariant
    float2 b0[TT], b1[TT];
    #pragma unroll
    for (int t = 0; t < TT; ++t) {
        b0[t] = ring[t][l0];
        b1[t] = ring[t][l0 + 256];
    }

    int w0base = (l0 - kbase - 7) & (NN - 1);        // window start, half 0
    int w1base = (l0 + 256 - kbase - 7) & (NN - 1);  // window start, half 1

    float r0[8], i0[8], r1[8], i1[8];

    // t = 0 peeled: initializes accumulators (no zero-init pass)
    {
        const float2* rt = ring[0];
        float2 cw0[8], cw1[8], av[8];
        #pragma unroll
        for (int j = 0; j < 8; ++j) {
            cw0[j] = rt[w0base + j];
            cw1[j] = rt[w1base + j];
            av[j]  = rt[kbase + j];   // wave-uniform broadcast
        }
        #pragma unroll
        for (int kk = 0; kk < 8; ++kk) {
            float2 a  = av[kk];
            float2 c0 = cw0[7 - kk];
            float2 c1 = cw1[7 - kk];
            float ur0 = a.x * c0.x - a.y * c0.y;
            float ui0 = a.x * c0.y + a.y * c0.x;
            r0[kk] = ur0 * b0[0].x + ui0 * b0[0].y;
            i0[kk] = ui0 * b0[0].x - ur0 * b0[0].y;
            float ur1 = a.x * c1.x - a.y * c1.y;
            float ui1 = a.x * c1.y + a.y * c1.x;
            r1[kk] = ur1 * b1[0].x + ui1 * b1[0].y;
            i1[kk] = ui1 * b1[0].x - ur1 * b1[0].y;
        }
    }

    #pragma unroll
    for (int t = 1; t < TT; ++t) {
        const float2* rt = ring[t];
        float2 cw0[8], cw1[8], av[8];
        #pragma unroll
        for (int j = 0; j < 8; ++j) {
            cw0[j] = rt[w0base + j];
            cw1[j] = rt[w1base + j];
            av[j]  = rt[kbase + j];
        }
        #pragma unroll
        for (int kk = 0; kk < 8; ++kk) {
            float2 a  = av[kk];
            float2 c0 = cw0[7 - kk];
            float2 c1 = cw1[7 - kk];
            float ur0 = a.x * c0.x - a.y * c0.y;
            float ui0 = a.x * c0.y + a.y * c0.x;
            r0[kk] += ur0 * b0[t].x + ui0 * b0[t].y;
            i0[kk] += ui0 * b0[t].x - ur0 * b0[t].y;
            float ur1 = a.x * c1.x - a.y * c1.y;
            float ui1 = a.x * c1.y + a.y * c1.x;
            r1[kk] += ur1 * b1[t].x + ui1 * b1[t].y;
            i1[kk] += ui1 * b1[t].x - ur1 * b1[t].y;
        }
    }

    float* outb = out + (size_t)b * 2 * NN * NN;
    #pragma unroll
    for (int kk = 0; kk < 8; ++kk) {
        size_t rk = (size_t)(kbase + kk) * NN + l0;
        __builtin_nontemporal_store(r0[kk] * 0.25f, &outb[rk]);                 // re, l0
        __builtin_nontemporal_store(r1[kk] * 0.25f, &outb[rk + 256]);           // re, l0+256
        __builtin_nontemporal_store(i0[kk] * 0.25f, &outb[NN * NN + rk]);       // im, l0
        __builtin_nontemporal_store(i1[kk] * 0.25f, &outb[NN * NN + rk + 256]); // im, l0+256
    }
}

extern "C" void kernel_launch(void* const* d_in, const int* in_sizes, int n_in,
                              void* d_out, int out_size, void* d_ws, size_t ws_size,
                              hipStream_t stream) {
    const float* target = (const float*)d_in[0];
    float* out = (float*)d_out;
    // workspace: y spectrum, B*T*N complex64 = 512 KiB
    float2* y = (float2*)d_ws;
    float* tail = out + (size_t)BB * 2 * NN * NN;  // target passthrough

    dft_kernel<<<BB * TT * 4, 256, 0, stream>>>(target, y, tail);
    bispec_kernel<<<BB * 64, 256, 0, stream>>>(y, out);
}

// Round 6
// 90.099 us; speedup vs baseline: 1.0646x; 1.0646x over previous
//
#include <hip/hip_runtime.h>
#include <math.h>

// BispectrumCalculator:
//   y = fft(target)  [B,T,N] complex
//   Bx[k,l] = y[k] * conj(y[l]) * y[(l-k) mod N]
//   source = stack([Bx.re, Bx.im], ch).mean(T)  -> [B, 2, N, N]
//   outputs: (source, target)  -> d_out = source flat (16,777,216) ++ target flat (65,536)
//
// Window model (r2-r5): harness re-poison of d_ws (269 MB, ~46us) + d_out
// (67 MB, ~11us) is inside the measured window; controllable slice ~30us.
// r5 post-mortem: padded-ring + nontemporal stores + t0-peel REGRESSED
// (90.3 -> 95.9us); this round is a clean revert to the r4-best bispec
// (doubled ring, zero-init, plain cached stores) to re-establish 90.3.

#define NN 512
#define TT 4
#define BB 32

// ---------------------------------------------------------------------------
// Kernel A: DFT-512 per (b,t), n-split for occupancy (unchanged from r4).
// Grid = 512 blocks x 256 threads; tid = nh*128+kl, k = kq*128+kl.
// Rotor seeds via exact mod-512 phase reduction; nh=1 partials via LDS.
// kq==0 also copies the target row to the output tail (fused passthrough).
// ---------------------------------------------------------------------------
__global__ __launch_bounds__(256) void dft_kernel(const float* __restrict__ x,
                                                  float2* __restrict__ y,
                                                  float* __restrict__ tail) {
    __shared__ float2 part[128];

    int bt = blockIdx.x >> 2;
    int kq = blockIdx.x & 3;
    int kl = threadIdx.x & 127;
    int nh = threadIdx.x >> 7;
    int k  = (kq << 7) | kl;
    const float* xp = x + (size_t)bt * NN;

    if (kq == 0 && nh == 0) {
        ((float4*)(tail + (size_t)bt * NN))[kl] = ((const float4*)xp)[kl];
    }

    int n0 = nh << 8;  // 0 or 256
    const float twopi_n = -2.0f * (float)M_PI / (float)NN;

    float2 w0, w1, w2, w3;
    float s4, c4;
    {
        int m0 = (k * (n0 + 0)) & (NN - 1);
        int m1 = (k * (n0 + 1)) & (NN - 1);
        int m2 = (k * (n0 + 2)) & (NN - 1);
        int m3 = (k * (n0 + 3)) & (NN - 1);
        int m4 = (k * 4) & (NN - 1);
        sincosf(twopi_n * (float)m0, &w0.y, &w0.x);
        sincosf(twopi_n * (float)m1, &w1.y, &w1.x);
        sincosf(twopi_n * (float)m2, &w2.y, &w2.x);
        sincosf(twopi_n * (float)m3, &w3.y, &w3.x);
        sincosf(twopi_n * (float)m4, &s4, &c4);
    }

    float2 a0 = make_float2(0.f, 0.f), a1 = a0, a2 = a0, a3 = a0;

    #pragma unroll 4
    for (int n = n0; n < n0 + 256; n += 4) {
        float x0 = xp[n];
        float x1 = xp[n + 1];
        float x2 = xp[n + 2];
        float x3 = xp[n + 3];
        a0.x += x0 * w0.x; a0.y += x0 * w0.y;
        a1.x += x1 * w1.x; a1.y += x1 * w1.y;
        a2.x += x2 * w2.x; a2.y += x2 * w2.y;
        a3.x += x3 * w3.x; a3.y += x3 * w3.y;
        float t;
        t = w0.x * c4 - w0.y * s4; w0.y = w0.x * s4 + w0.y * c4; w0.x = t;
        t = w1.x * c4 - w1.y * s4; w1.y = w1.x * s4 + w1.y * c4; w1.x = t;
        t = w2.x * c4 - w2.y * s4; w2.y = w2.x * s4 + w2.y * c4; w2.x = t;
        t = w3.x * c4 - w3.y * s4; w3.y = w3.x * s4 + w3.y * c4; w3.x = t;
    }

    float re = (a0.x + a1.x) + (a2.x + a3.x);
    float im = (a0.y + a1.y) + (a2.y + a3.y);

    if (nh == 1) {
        part[kl] = make_float2(re, im);
    }
    __syncthreads();
    if (nh == 0) {
        float2 p = part[kl];
        y[(size_t)bt * NN + k] = make_float2(re + p.x, im + p.y);
    }
}

// ---------------------------------------------------------------------------
// Kernel B: bispectrum, register-sliding-window (byte-identical to r4 best).
// Grid = B * 64 blocks of 256 threads; block = one b, 8 consecutive k-rows.
// Doubled LDS ring per t removes the mod-512 wrap -> 8-wide contiguous
// c-windows read once per t, reused across 8 k. Near the 64 MiB store floor.
// (r5 variants — padded ring / nt stores / t0 peel — regressed; keep this.)
// ---------------------------------------------------------------------------
__global__ __launch_bounds__(256) void bispec_kernel(const float2* __restrict__ y,
                                                     float* __restrict__ out) {
    __shared__ float2 ring[TT * 2 * NN];  // 32 KiB, doubled ring per t

    int b     = blockIdx.x >> 6;
    int kbase = (blockIdx.x & 63) << 3;
    int tid   = threadIdx.x;

    // stage y[b] -> doubled LDS ring (global: [t][256] float4)
    const float4* src = (const float4*)(y + (size_t)b * TT * NN);
    float4* dst4 = (float4*)ring;
    #pragma unroll
    for (int i = 0; i < 4; ++i) {
        int g = tid + 256 * i;          // [0,1024)
        int t = g >> 8;
        int j = g & 255;
        float4 v = src[g];
        dst4[(t << 9) + j]       = v;
        dst4[(t << 9) + j + 256] = v;
    }
    __syncthreads();

    int l0 = tid;  // second l is l0 + 256

    // conj-source values, k-invariant
    float2 b0[TT], b1[TT];
    #pragma unroll
    for (int t = 0; t < TT; ++t) {
        b0[t] = ring[(t << 10) + l0];
        b1[t] = ring[(t << 10) + l0 + 256];
    }

    float r0[8], i0[8], r1[8], i1[8];
    #pragma unroll
    for (int kk = 0; kk < 8; ++kk) { r0[kk] = i0[kk] = r1[kk] = i1[kk] = 0.f; }

    int w0base = (l0 - kbase - 7) & (NN - 1);        // window start, half 0
    int w1base = (l0 + 256 - kbase - 7) & (NN - 1);  // window start, half 1

    #pragma unroll
    for (int t = 0; t < TT; ++t) {
        const float2* rt = ring + (t << 10);
        float2 cw0[8], cw1[8], av[8];
        #pragma unroll
        for (int j = 0; j < 8; ++j) {
            cw0[j] = rt[w0base + j];
            cw1[j] = rt[w1base + j];
            av[j]  = rt[kbase + j];   // wave-uniform broadcast
        }
        #pragma unroll
        for (int kk = 0; kk < 8; ++kk) {
            float2 a  = av[kk];
            float2 c0 = cw0[7 - kk];
            float2 c1 = cw1[7 - kk];
            float ur0 = a.x * c0.x - a.y * c0.y;
            float ui0 = a.x * c0.y + a.y * c0.x;
            r0[kk] += ur0 * b0[t].x + ui0 * b0[t].y;
            i0[kk] += ui0 * b0[t].x - ur0 * b0[t].y;
            float ur1 = a.x * c1.x - a.y * c1.y;
            float ui1 = a.x * c1.y + a.y * c1.x;
            r1[kk] += ur1 * b1[t].x + ui1 * b1[t].y;
            i1[kk] += ui1 * b1[t].x - ur1 * b1[t].y;
        }
    }

    float* outb = out + (size_t)b * 2 * NN * NN;
    #pragma unroll
    for (int kk = 0; kk < 8; ++kk) {
        size_t rk = (size_t)(kbase + kk) * NN + l0;
        outb[rk]                 = r0[kk] * 0.25f;  // real ch, l0
        outb[rk + 256]           = r1[kk] * 0.25f;  // real ch, l0+256
        outb[NN * NN + rk]       = i0[kk] * 0.25f;  // imag ch, l0
        outb[NN * NN + rk + 256] = i1[kk] * 0.25f;  // imag ch, l0+256
    }
}

extern "C" void kernel_launch(void* const* d_in, const int* in_sizes, int n_in,
                              void* d_out, int out_size, void* d_ws, size_t ws_size,
                              hipStream_t stream) {
    const float* target = (const float*)d_in[0];
    float* out = (float*)d_out;
    // workspace: y spectrum, B*T*N complex64 = 512 KiB
    float2* y = (float2*)d_ws;
    float* tail = out + (size_t)BB * 2 * NN * NN;  // target passthrough

    dft_kernel<<<BB * TT * 4, 256, 0, stream>>>(target, y, tail);
    bispec_kernel<<<BB * 64, 256, 0, stream>>>(y, out);
}